// Round 12
// baseline (160.773 us; speedup 1.0000x reference)
//
#include <hip/hip_runtime.h>
#include <hip/hip_fp16.h>
#include <stdint.h>
#include <math.h>

#define KB 512
#define KT 2048
#define KS 16
#define KPD 4

typedef _Float16 f16;
typedef _Float16 f16x4v __attribute__((ext_vector_type(4)));
typedef _Float16 f16x8 __attribute__((ext_vector_type(8)));
typedef float f32x4 __attribute__((ext_vector_type(4)));

#define MFMA16(A, B, C) __builtin_amdgcn_mfma_f32_16x16x32_f16(A, B, C, 0, 0, 0)

// ---------------- shared helpers ----------------
__device__ __forceinline__ float softplus_f(float x) {
    float ax = fabsf(x);
    float e  = __expf(-ax);
    return fmaxf(x, 0.0f) + __logf(1.0f + e);
}
__device__ __forceinline__ float sigmoid_f(float x) {
    return __builtin_amdgcn_rcpf(1.0f + __expf(-x));
}
__device__ __forceinline__ float h2f_lo(uint32_t w) {
    return __half2float(__ushort_as_half((unsigned short)(w & 0xffffu)));
}
__device__ __forceinline__ float h2f_hi(uint32_t w) {
    return __half2float(__ushort_as_half((unsigned short)(w >> 16)));
}
__device__ __forceinline__ f16x8 zero8() {
    f16x8 v;
#pragma unroll
    for (int i = 0; i < 8; ++i) v[i] = (f16)0;
    return v;
}

// ---------------- K1: MFMA MLPs — R8 wave body, 4 independent waves/block ----------------
// Each wave: 64 (b,t) rows. Per n-subtile (16 rows): GEMM1 H-slice -> private LDS
// -> GEMM2 -> direct stores (R8 pattern, proven non-amplifying). No arrays held
// across the n-loop (no spills); no __syncthreads.
#define HRS 174   // H row stride in f16 = 87 dwords (odd -> bank-alias-free)
#define NW  4     // independent waves per block

__global__ __launch_bounds__(64 * NW) void mlp_kernel(
    const float* __restrict__ p,
    const float* __restrict__ Wq1, const float* __restrict__ bq1,
    const float* __restrict__ Wq2, const float* __restrict__ bq2,
    const float* __restrict__ Wr1, const float* __restrict__ br1,
    const float* __restrict__ Wr2, const float* __restrict__ br2,
    const float* __restrict__ Wg1, const float* __restrict__ bg1,
    const float* __restrict__ Wg2, const float* __restrict__ bg2,
    uint32_t* __restrict__ qr_ws, float* __restrict__ g_ws)
{
    __shared__ __align__(16) f16 HlA[NW][16][HRS];   // per-wave n-slice
    __shared__ __align__(16) f16 PlA[NW][64][4];     // per-wave p tile

    const int wv = threadIdx.x >> 6;
    const int l = threadIdx.x & 63;
    const int g = l >> 4;
    const int c = l & 15;
    const int row0 = (blockIdx.x * NW + wv) * 64;
    const int b = row0 >> 11;
    const int t0 = row0 & (KT - 1);

    f16 (*__restrict__ Hl)[HRS] = HlA[wv];
    f16 (*__restrict__ Pl)[4]   = PlA[wv];

    // ---- const A-frags: W1cat^T, 10 M-tiles (A[row=hcol][k=pd], k>=4 zero) ----
    f16x8 fA1[10];
#pragma unroll
    for (int m = 0; m < 10; ++m) {
        const float* W = (m < 4) ? (Wq1 + m * 16)
                       : (m < 8) ? (Wr1 + (m - 4) * 16)
                                 : (Wg1 + (m - 8) * 16);
        const int ld = (m < 8) ? 64 : 32;
        float w0 = W[0 * ld + c], w1 = W[1 * ld + c],
              w2 = W[2 * ld + c], w3 = W[3 * ld + c];
        f16x8 a = zero8();
        if (g == 0) { a[0] = (f16)w0; a[1] = (f16)w1; a[2] = (f16)w2; a[3] = (f16)w3; }
        fA1[m] = a;
    }

    // ---- const A-frags: W2cat^T ----
    f16x8 fA2[5];
#pragma unroll
    for (int i = 0; i < 4; ++i) {
        const float* W = (i < 2) ? Wq2 : Wr2;
        const int kb = (i & 1) * 32;
        f16x8 a;
#pragma unroll
        for (int j = 0; j < 8; ++j) a[j] = (f16)W[(kb + g * 8 + j) * 16 + c];
        fA2[i] = a;
    }
    {
        f16x8 a = zero8();
        if (c == 0) {
#pragma unroll
            for (int j = 0; j < 8; ++j) a[j] = (f16)Wg2[g * 8 + j];
        }
        fA2[4] = a;
    }

    const float bQ0 = bq2[g * 4 + 0], bQ1 = bq2[g * 4 + 1],
                bQ2 = bq2[g * 4 + 2], bQ3 = bq2[g * 4 + 3];
    const float bR0 = br2[g * 4 + 0], bR1 = br2[g * 4 + 1],
                bR2 = br2[g * 4 + 2], bR3 = br2[g * 4 + 3];
    const float bG = bg2[0];

    // ---- stage p tile (f16) ----
    {
        const float4 pv = *reinterpret_cast<const float4*>(p + (size_t)(row0 + l) * KPD);
        f16x4v v; v[0] = (f16)pv.x; v[1] = (f16)pv.y; v[2] = (f16)pv.z; v[3] = (f16)pv.w;
        *reinterpret_cast<f16x4v*>(&Pl[l][0]) = v;
    }
    asm volatile("s_waitcnt lgkmcnt(0)" ::: "memory");
    __builtin_amdgcn_sched_barrier(0);

#pragma unroll
    for (int n = 0; n < 4; ++n) {
        // GEMM1 B-frag (P: B[k=pd][col=bt], k>=4 zero)
        f16x8 fBP = zero8();
        if (g == 0) {
            f16x4v q = *reinterpret_cast<const f16x4v*>(&Pl[n * 16 + c][0]);
            fBP[0] = q[0]; fBP[1] = q[1]; fBP[2] = q[2]; fBP[3] = q[3];
        }

        // ---- GEMM1: 10 MFMA, relu+pack -> Hl slice ----
#pragma unroll
        for (int m = 0; m < 10; ++m) {
            const float* bs = (m < 4) ? (bq1 + m * 16)
                            : (m < 8) ? (br1 + (m - 4) * 16)
                                      : (bg1 + (m - 8) * 16);
            f32x4 acc;
            acc[0] = bs[g * 4 + 0]; acc[1] = bs[g * 4 + 1];
            acc[2] = bs[g * 4 + 2]; acc[3] = bs[g * 4 + 3];
            acc = MFMA16(fA1[m], fBP, acc);
            auto h01 = __builtin_amdgcn_cvt_pkrtz(fmaxf(acc[0], 0.f), fmaxf(acc[1], 0.f));
            auto h23 = __builtin_amdgcn_cvt_pkrtz(fmaxf(acc[2], 0.f), fmaxf(acc[3], 0.f));
            uint2 w;
            __builtin_memcpy(&w.x, &h01, 4);
            __builtin_memcpy(&w.y, &h23, 4);
            *reinterpret_cast<uint2*>(&Hl[c][m * 16 + g * 4]) = w;
        }
        asm volatile("s_waitcnt lgkmcnt(0)" ::: "memory");
        __builtin_amdgcn_sched_barrier(0);

        // ---- GEMM2 ----
        f16x8 fb0 = *reinterpret_cast<const f16x8*>(&Hl[c][0 * 32 + g * 8]);
        f16x8 fb1 = *reinterpret_cast<const f16x8*>(&Hl[c][1 * 32 + g * 8]);
        f16x8 fb2 = *reinterpret_cast<const f16x8*>(&Hl[c][2 * 32 + g * 8]);
        f16x8 fb3 = *reinterpret_cast<const f16x8*>(&Hl[c][3 * 32 + g * 8]);
        f16x8 fb4 = *reinterpret_cast<const f16x8*>(&Hl[c][4 * 32 + g * 8]);

        f32x4 aq; aq[0] = bQ0; aq[1] = bQ1; aq[2] = bQ2; aq[3] = bQ3;
        aq = MFMA16(fA2[0], fb0, aq);
        aq = MFMA16(fA2[1], fb1, aq);
        f32x4 ar; ar[0] = bR0; ar[1] = bR1; ar[2] = bR2; ar[3] = bR3;
        ar = MFMA16(fA2[2], fb2, ar);
        ar = MFMA16(fA2[3], fb3, ar);
        f32x4 ag; ag[0] = 0.f; ag[1] = 0.f; ag[2] = 0.f; ag[3] = 0.f;
        ag = MFMA16(fA2[4], fb4, ag);

        uint32_t* qdst = qr_ws + ((size_t)b * KS + g * 4) * KT + t0 + n * 16 + c;
#pragma unroll
        for (int i = 0; i < 4; ++i) {
            float Qv = softplus_f(aq[i]) + 1e-8f;
            float Rv = softplus_f(ar[i]) + 1e-8f;
            auto pk = __builtin_amdgcn_cvt_pkrtz(Qv, Rv);
            uint32_t w; __builtin_memcpy(&w, &pk, 4);
            qdst[(size_t)i * KT] = w;
        }
        if (g == 0)
            g_ws[(size_t)b * KT + t0 + n * 16 + c] = sigmoid_f(ag[0] + bG);
        asm volatile("s_waitcnt lgkmcnt(0)" ::: "memory");  // fb reads done before next n's Hl write
        __builtin_amdgcn_sched_barrier(0);
    }
}

// ---------------- K2: parallel-scan Kalman (Mobius + affine) — unchanged ----------------
#define QT 512
#define NQ (KT / QT)
#define CL 8

__global__ __launch_bounds__(1024) void scan_kernel(
    const uint32_t* __restrict__ qr_ws, const float* __restrict__ g_ws,
    const float* __restrict__ z, const float* __restrict__ mu0,
    const float* __restrict__ P0, float* __restrict__ out)
{
    __shared__ float smem[QT * 17 + QT];
    float* zmu = smem;
    float* gl  = smem + QT * 17;

    const int b = blockIdx.x;
    const int tid = threadIdx.x;
    const int lane = tid & 63;
    const int s = tid >> 6;

    const uint32_t* qrow = qr_ws + (size_t)(b * KS + s) * KT;
    const float* zb = z + (size_t)b * KT * KS;
    const float* gb = g_ws + (size_t)b * KT;
    float* ob = out + (size_t)b * KT * KS;

    float P_q  = P0[b * KS + s];
    float mu_q = mu0[b * KS + s];

    for (int q = 0; q < NQ; ++q) {
        const int t0 = q * QT;

        {
            const float4* zq = reinterpret_cast<const float4*>(zb + (size_t)t0 * KS);
#pragma unroll
            for (int v = 0; v < 2; ++v) {
                int k = tid * 2 + v;
                float4 w = zq[k];
                int t = k >> 2, s0 = (k & 3) << 2;
                zmu[t * 17 + s0 + 0] = w.x;
                zmu[t * 17 + s0 + 1] = w.y;
                zmu[t * 17 + s0 + 2] = w.z;
                zmu[t * 17 + s0 + 3] = w.w;
            }
            if (tid < QT) gl[tid] = gb[t0 + tid];
        }
        __syncthreads();

        uint32_t qr[CL];
        {
            const uint4* qp = reinterpret_cast<const uint4*>(qrow + t0 + lane * CL);
            uint4 u0 = qp[0], u1 = qp[1];
            qr[0] = u0.x; qr[1] = u0.y; qr[2] = u0.z; qr[3] = u0.w;
            qr[4] = u1.x; qr[5] = u1.y; qr[6] = u1.z; qr[7] = u1.w;
        }
        float c00 = 1.f, c01 = 0.f, c10 = 0.f, c11 = 1.f;
#pragma unroll
        for (int i = 0; i < CL; ++i) {
            float Q = h2f_lo(qr[i]), R = h2f_hi(qr[i]);
            float ta = fmaf(Q, c10, c00);
            float tb = fmaf(Q, c11, c01);
            float n10 = fmaf(Q + R, c10, c00);
            float n11 = fmaf(Q + R, c11, c01);
            c00 = R * ta; c01 = R * tb; c10 = n10; c11 = n11;
        }
        float rn = __builtin_amdgcn_rcpf(c11);
        float ma = c00 * rn, mb = c01 * rn, mc = c10 * rn;

#pragma unroll
        for (int r = 0; r < 6; ++r) {
            const int d = 1 << r;
            float pa = __shfl_up(ma, d);
            float pb = __shfl_up(mb, d);
            float pc = __shfl_up(mc, d);
            float na = fmaf(ma, pa, mb * pc);
            float nb = fmaf(ma, pb, mb);
            float nc = fmaf(mc, pa, pc);
            float nd = fmaf(mc, pb, 1.f);
            float rr = __builtin_amdgcn_rcpf(nd);
            bool act = (lane >= d);
            ma = act ? na * rr : ma;
            mb = act ? nb * rr : mb;
            mc = act ? nc * rr : mc;
        }
        float ea = __shfl_up(ma, 1);
        float eb = __shfl_up(mb, 1);
        float ec = __shfl_up(mc, 1);
        if (lane == 0) { ea = 1.f; eb = 0.f; ec = 0.f; }
        float P = fmaf(ea, P_q, eb) * __builtin_amdgcn_rcpf(fmaf(ec, P_q, 1.f));

        float av[CL], bw[CL];
        float A = 1.f, Bv = 0.f;
#pragma unroll
        for (int i = 0; i < CL; ++i) {
            float Q = h2f_lo(qr[i]), R = h2f_hi(qr[i]);
            float Pp = P + Q;
            float K0 = Pp * __builtin_amdgcn_rcpf(Pp + R);
            float Kk = __builtin_amdgcn_fmed3f(K0, 1e-6f, 0.95f);
            int t = lane * CL + i;
            float g = gl[t];
            float gk = g * Kk;
            float zv = zmu[t * 17 + s];
            av[i] = 1.f - gk;
            bw[i] = gk * zv;
            P = fmaf(-Kk, Pp, Pp);
            A = A * av[i];
            Bv = fmaf(av[i], Bv, bw[i]);
        }
        float P_end = __shfl(P, 63);

#pragma unroll
        for (int r = 0; r < 6; ++r) {
            const int d = 1 << r;
            float pA = __shfl_up(A, d);
            float pB = __shfl_up(Bv, d);
            float nA = A * pA;
            float nB = fmaf(A, pB, Bv);
            bool act = (lane >= d);
            A  = act ? nA : A;
            Bv = act ? nB : Bv;
        }
        float eA = __shfl_up(A, 1);
        float eB = __shfl_up(Bv, 1);
        if (lane == 0) { eA = 1.f; eB = 0.f; }
        float mu = fmaf(eA, mu_q, eB);

        __syncthreads();

#pragma unroll
        for (int i = 0; i < CL; ++i) {
            mu = fmaf(av[i], mu, bw[i]);
            zmu[(lane * CL + i) * 17 + s] = mu;
        }
        float mu_end = __shfl(mu, 63);
        __syncthreads();

#pragma unroll
        for (int v = 0; v < 2; ++v) {
            int k = tid * 2 + v;
            int t = k >> 2, s0 = (k & 3) << 2;
            float4 w;
            w.x = zmu[t * 17 + s0 + 0];
            w.y = zmu[t * 17 + s0 + 1];
            w.z = zmu[t * 17 + s0 + 2];
            w.w = zmu[t * 17 + s0 + 3];
            *reinterpret_cast<float4*>(ob + (size_t)(t0 + t) * KS + s0) = w;
        }
        P_q  = P_end;
        mu_q = mu_end;
        __syncthreads();
    }
}

// ---------------- fallback: fused kernel (if ws too small) ----------------
#define KTT 128
#define KNT (KT / KTT)
#define SROW (KS + 1)

__device__ __forceinline__ void mlp16(const float4 pv,
    const float* __restrict__ W1, const float* __restrict__ b1,
    const float* __restrict__ W2, const float* __restrict__ b2,
    float* __restrict__ acc)
{
#pragma unroll
    for (int j = 0; j < KS; ++j) acc[j] = b2[j];
#pragma unroll 4
    for (int k = 0; k < 64; ++k) {
        float hk = b1[k];
        hk = fmaf(pv.x, W1[k],       hk);
        hk = fmaf(pv.y, W1[64 + k],  hk);
        hk = fmaf(pv.z, W1[128 + k], hk);
        hk = fmaf(pv.w, W1[192 + k], hk);
        hk = fmaxf(hk, 0.0f);
#pragma unroll
        for (int j = 0; j < KS; ++j) acc[j] = fmaf(hk, W2[k * KS + j], acc[j]);
    }
}

__global__ __launch_bounds__(320, 2) void kalman_fused(
    const float* __restrict__ z, const float* __restrict__ p,
    const float* __restrict__ mu0, const float* __restrict__ P0,
    const float* __restrict__ Wq1, const float* __restrict__ bq1,
    const float* __restrict__ Wq2, const float* __restrict__ bq2,
    const float* __restrict__ Wr1, const float* __restrict__ br1,
    const float* __restrict__ Wr2, const float* __restrict__ br2,
    const float* __restrict__ Wg1, const float* __restrict__ bg1,
    const float* __restrict__ Wg2, const float* __restrict__ bg2,
    float* __restrict__ out)
{
    __shared__ float sQ[2][KTT][SROW];
    __shared__ float sR[2][KTT][SROW];
    __shared__ float sZf[2][KTT][KS];
    __shared__ float sGf[2][KTT];

    const int b = blockIdx.x;
    const int tid = threadIdx.x;
    const float* __restrict__ zb = z + (size_t)b * KT * KS;
    const float* __restrict__ pb = p + (size_t)b * KT * KPD;
    float* __restrict__ outb = out + (size_t)b * KT * KS;

    const bool is_mlp = (tid < 256);

    auto do_mlp_tile = [&](int tile, int buf) {
        const int tt = tid & (KTT - 1);
        const int t = tile * KTT + tt;
        const float4 pv = *reinterpret_cast<const float4*>(pb + (size_t)t * KPD);
        float acc[KS];
        if (tid < KTT) {
            mlp16(pv, Wq1, bq1, Wq2, bq2, acc);
#pragma unroll
            for (int j = 0; j < KS; ++j)
                sQ[buf][tt][j] = softplus_f(acc[j]) + 1e-8f;
            float ag = bg2[0];
#pragma unroll 8
            for (int k = 0; k < 32; ++k) {
                float hk = bg1[k];
                hk = fmaf(pv.x, Wg1[k],      hk);
                hk = fmaf(pv.y, Wg1[32 + k], hk);
                hk = fmaf(pv.z, Wg1[64 + k], hk);
                hk = fmaf(pv.w, Wg1[96 + k], hk);
                hk = fmaxf(hk, 0.0f);
                ag = fmaf(hk, Wg2[k], ag);
            }
            sGf[buf][tt] = sigmoid_f(ag);
        } else {
            mlp16(pv, Wr1, br1, Wr2, br2, acc);
#pragma unroll
            for (int j = 0; j < KS; ++j)
                sR[buf][tt][j] = softplus_f(acc[j]) + 1e-8f;
        }
        const float4* __restrict__ zt =
            reinterpret_cast<const float4*>(zb + (size_t)tile * KTT * KS);
        float4* __restrict__ zd = reinterpret_cast<float4*>(&sZf[buf][0][0]);
        zd[tid] = zt[tid];
        zd[tid + 256] = zt[tid + 256];
    };

    float mu = 0.0f, Pv = 0.0f;
    if (!is_mlp) {
        const int lane = tid - 256;
        if (lane < KS) {
            mu = mu0[(size_t)b * KS + lane];
            Pv = P0[(size_t)b * KS + lane];
        }
    }

    if (is_mlp) do_mlp_tile(0, 0);
    __syncthreads();

    for (int k = 0; k < KNT; ++k) {
        const int cur = k & 1;
        if (is_mlp) {
            if (k + 1 < KNT) do_mlp_tile(k + 1, cur ^ 1);
        } else {
            const int lane = tid - 256;
            if (lane < KS) {
                const int s = lane;
                for (int tt = 0; tt < KTT; ++tt) {
                    const float Ppred = Pv + sQ[cur][tt][s];
                    float Kk = Ppred * __builtin_amdgcn_rcpf(Ppred + sR[cur][tt][s]);
                    Kk = __builtin_amdgcn_fmed3f(Kk, 1e-6f, 0.95f);
                    mu = fmaf(sGf[cur][tt] * Kk, sZf[cur][tt][s] - mu, mu);
                    Pv = fmaf(-Kk, Ppred, Ppred);
                    outb[(size_t)(k * KTT + tt) * KS + s] = mu;
                }
            }
        }
        __syncthreads();
    }
}

// ---------------- launcher ----------------
extern "C" void kernel_launch(void* const* d_in, const int* in_sizes, int n_in,
                              void* d_out, int out_size, void* d_ws, size_t ws_size,
                              hipStream_t stream) {
    const float* z   = (const float*)d_in[0];
    const float* p   = (const float*)d_in[1];
    const float* mu0 = (const float*)d_in[2];
    const float* P0  = (const float*)d_in[3];
    const float* Wq1 = (const float*)d_in[4];
    const float* bq1 = (const float*)d_in[5];
    const float* Wq2 = (const float*)d_in[6];
    const float* bq2 = (const float*)d_in[7];
    const float* Wr1 = (const float*)d_in[8];
    const float* br1 = (const float*)d_in[9];
    const float* Wr2 = (const float*)d_in[10];
    const float* br2 = (const float*)d_in[11];
    const float* Wg1 = (const float*)d_in[12];
    const float* bg1 = (const float*)d_in[13];
    const float* Wg2 = (const float*)d_in[14];
    const float* bg2 = (const float*)d_in[15];
    float* out = (float*)d_out;

    const size_t QR_BYTES = (size_t)KB * KS * KT * 4;   // 67,108,864
    const size_t G_BYTES  = (size_t)KB * KT * 4;        //  4,194,304

    if (ws_size >= QR_BYTES + G_BYTES) {
        uint32_t* qr_ws = (uint32_t*)d_ws;
        float* g_ws = (float*)((char*)d_ws + QR_BYTES);
        hipLaunchKernelGGL(mlp_kernel, dim3((KB * KT) / (64 * NW)), dim3(64 * NW),
                           0, stream,
                           p, Wq1, bq1, Wq2, bq2, Wr1, br1, Wr2, br2,
                           Wg1, bg1, Wg2, bg2, qr_ws, g_ws);
        hipLaunchKernelGGL(scan_kernel, dim3(KB), dim3(1024), 0, stream,
                           qr_ws, g_ws, z, mu0, P0, out);
    } else {
        hipLaunchKernelGGL(kalman_fused, dim3(KB), dim3(320), 0, stream,
                           z, p, mu0, P0, Wq1, bq1, Wq2, bq2,
                           Wr1, br1, Wr2, br2, Wg1, bg1, Wg2, bg2, out);
    }
}

// Round 13
// 106.226 us; speedup vs baseline: 1.5135x; 1.5135x over previous
//
#include <hip/hip_runtime.h>
#include <hip/hip_fp16.h>
#include <stdint.h>
#include <math.h>

#define KB 512
#define KT 2048
#define KS 16
#define KPD 4

typedef _Float16 f16;
typedef _Float16 f16x4v __attribute__((ext_vector_type(4)));
typedef _Float16 f16x8 __attribute__((ext_vector_type(8)));
typedef float f32x4 __attribute__((ext_vector_type(4)));

#define MFMA16(A, B, C) __builtin_amdgcn_mfma_f32_16x16x32_f16(A, B, C, 0, 0, 0)

// ---------------- shared helpers ----------------
__device__ __forceinline__ float softplus_f(float x) {
    float ax = fabsf(x);
    float e  = __expf(-ax);
    return fmaxf(x, 0.0f) + __logf(1.0f + e);
}
__device__ __forceinline__ float sigmoid_f(float x) {
    return __builtin_amdgcn_rcpf(1.0f + __expf(-x));
}
__device__ __forceinline__ float h2f_lo(uint32_t w) {
    return __half2float(__ushort_as_half((unsigned short)(w & 0xffffu)));
}
__device__ __forceinline__ float h2f_hi(uint32_t w) {
    return __half2float(__ushort_as_half((unsigned short)(w >> 16)));
}
__device__ __forceinline__ f16x8 zero8() {
    f16x8 v;
#pragma unroll
    for (int i = 0; i < 8; ++i) v[i] = (f16)0;
    return v;
}

// ---------------- K1: MFMA MLPs — R8 dataflow + ping-pong H slices ----------------
// 1 wave per 64 (b,t) rows. Software pipeline over n: GEMM1(n+1) -> buf^1 while
// GEMM2(n) <- buf. No manual fences in the loop: buffers are compile-time
// disambiguated, DS pipe is in-order per wave, compiler inserts counted lgkmcnt.
#define HRS 168   // H row stride in f16

__global__ __launch_bounds__(64) void mlp_kernel(
    const float* __restrict__ p,
    const float* __restrict__ Wq1, const float* __restrict__ bq1,
    const float* __restrict__ Wq2, const float* __restrict__ bq2,
    const float* __restrict__ Wr1, const float* __restrict__ br1,
    const float* __restrict__ Wr2, const float* __restrict__ br2,
    const float* __restrict__ Wg1, const float* __restrict__ bg1,
    const float* __restrict__ Wg2, const float* __restrict__ bg2,
    uint32_t* __restrict__ qr_ws, float* __restrict__ g_ws)
{
    __shared__ __align__(16) f16 Hl[2][16][HRS];   // ping-pong n-slices, 10.5 KB
    __shared__ __align__(16) f16 Pl[64][4];

    const int l = threadIdx.x;
    const int g = l >> 4;
    const int c = l & 15;
    const int row0 = blockIdx.x * 64;
    const int b = row0 >> 11;
    const int t0 = row0 & (KT - 1);

    // ---- const A-frags: W1cat^T, 10 M-tiles (A[row=hcol][k=pd], k>=4 zero) ----
    f16x8 fA1[10];
#pragma unroll
    for (int m = 0; m < 10; ++m) {
        const float* W = (m < 4) ? (Wq1 + m * 16)
                       : (m < 8) ? (Wr1 + (m - 4) * 16)
                                 : (Wg1 + (m - 8) * 16);
        const int ld = (m < 8) ? 64 : 32;
        float w0 = W[0 * ld + c], w1 = W[1 * ld + c],
              w2 = W[2 * ld + c], w3 = W[3 * ld + c];
        f16x8 a = zero8();
        if (g == 0) { a[0] = (f16)w0; a[1] = (f16)w1; a[2] = (f16)w2; a[3] = (f16)w3; }
        fA1[m] = a;
    }

    // ---- const A-frags: W2cat^T ----
    f16x8 fA2[5];
#pragma unroll
    for (int i = 0; i < 4; ++i) {
        const float* W = (i < 2) ? Wq2 : Wr2;
        const int kb = (i & 1) * 32;
        f16x8 a;
#pragma unroll
        for (int j = 0; j < 8; ++j) a[j] = (f16)W[(kb + g * 8 + j) * 16 + c];
        fA2[i] = a;
    }
    {
        f16x8 a = zero8();
        if (c == 0) {
#pragma unroll
            for (int j = 0; j < 8; ++j) a[j] = (f16)Wg2[g * 8 + j];
        }
        fA2[4] = a;
    }

    const float bQ0 = bq2[g * 4 + 0], bQ1 = bq2[g * 4 + 1],
                bQ2 = bq2[g * 4 + 2], bQ3 = bq2[g * 4 + 3];
    const float bR0 = br2[g * 4 + 0], bR1 = br2[g * 4 + 1],
                bR2 = br2[g * 4 + 2], bR3 = br2[g * 4 + 3];
    const float bG = bg2[0];

    // ---- stage p tile (f16) ----
    {
        const float4 pv = *reinterpret_cast<const float4*>(p + (size_t)(row0 + l) * KPD);
        f16x4v v; v[0] = (f16)pv.x; v[1] = (f16)pv.y; v[2] = (f16)pv.z; v[3] = (f16)pv.w;
        *reinterpret_cast<f16x4v*>(&Pl[l][0]) = v;
    }
    asm volatile("s_waitcnt lgkmcnt(0)" ::: "memory");
    __builtin_amdgcn_sched_barrier(0);

    // ---- all GEMM1 B-frags up front (P: B[k=pd][col=bt], k>=4 zero) ----
    f16x8 fBP[4];
#pragma unroll
    for (int n = 0; n < 4; ++n) {
        f16x8 v = zero8();
        if (g == 0) {
            f16x4v q = *reinterpret_cast<const f16x4v*>(&Pl[n * 16 + c][0]);
            v[0] = q[0]; v[1] = q[1]; v[2] = q[2]; v[3] = q[3];
        }
        fBP[n] = v;
    }

    // GEMM1 for n-subtile -> Hl[buf]
    auto gemm1 = [&](int n, int buf) {
#pragma unroll
        for (int m = 0; m < 10; ++m) {
            const float* bs = (m < 4) ? (bq1 + m * 16)
                            : (m < 8) ? (br1 + (m - 4) * 16)
                                      : (bg1 + (m - 8) * 16);
            f32x4 acc;
            acc[0] = bs[g * 4 + 0]; acc[1] = bs[g * 4 + 1];
            acc[2] = bs[g * 4 + 2]; acc[3] = bs[g * 4 + 3];
            acc = MFMA16(fA1[m], fBP[n], acc);
            auto h01 = __builtin_amdgcn_cvt_pkrtz(fmaxf(acc[0], 0.f), fmaxf(acc[1], 0.f));
            auto h23 = __builtin_amdgcn_cvt_pkrtz(fmaxf(acc[2], 0.f), fmaxf(acc[3], 0.f));
            uint2 w;
            __builtin_memcpy(&w.x, &h01, 4);
            __builtin_memcpy(&w.y, &h23, 4);
            *reinterpret_cast<uint2*>(&Hl[buf][c][m * 16 + g * 4]) = w;
        }
    };

    // GEMM2 for n-subtile <- Hl[buf], epilogue + stores
    auto gemm2 = [&](int n, int buf) {
        f16x8 fb0 = *reinterpret_cast<const f16x8*>(&Hl[buf][c][0 * 32 + g * 8]);
        f16x8 fb1 = *reinterpret_cast<const f16x8*>(&Hl[buf][c][1 * 32 + g * 8]);
        f16x8 fb2 = *reinterpret_cast<const f16x8*>(&Hl[buf][c][2 * 32 + g * 8]);
        f16x8 fb3 = *reinterpret_cast<const f16x8*>(&Hl[buf][c][3 * 32 + g * 8]);
        f16x8 fb4 = *reinterpret_cast<const f16x8*>(&Hl[buf][c][4 * 32 + g * 8]);

        f32x4 aq; aq[0] = bQ0; aq[1] = bQ1; aq[2] = bQ2; aq[3] = bQ3;
        aq = MFMA16(fA2[0], fb0, aq);
        aq = MFMA16(fA2[1], fb1, aq);
        f32x4 ar; ar[0] = bR0; ar[1] = bR1; ar[2] = bR2; ar[3] = bR3;
        ar = MFMA16(fA2[2], fb2, ar);
        ar = MFMA16(fA2[3], fb3, ar);
        f32x4 ag; ag[0] = 0.f; ag[1] = 0.f; ag[2] = 0.f; ag[3] = 0.f;
        ag = MFMA16(fA2[4], fb4, ag);

        uint32_t* qdst = qr_ws + ((size_t)b * KS + g * 4) * KT + t0 + n * 16 + c;
#pragma unroll
        for (int i = 0; i < 4; ++i) {
            float Qv = softplus_f(aq[i]) + 1e-8f;
            float Rv = softplus_f(ar[i]) + 1e-8f;
            auto pk = __builtin_amdgcn_cvt_pkrtz(Qv, Rv);
            uint32_t w; __builtin_memcpy(&w, &pk, 4);
            qdst[(size_t)i * KT] = w;
        }
        if (g == 0)
            g_ws[(size_t)b * KT + t0 + n * 16 + c] = sigmoid_f(ag[0] + bG);
    };

    gemm1(0, 0);
#pragma unroll
    for (int n = 0; n < 4; ++n) {
        if (n < 3) gemm1(n + 1, (n + 1) & 1);
        gemm2(n, n & 1);
    }
}

// ---------------- K2: parallel-scan Kalman (Mobius + affine) — unchanged ----------------
#define QT 512
#define NQ (KT / QT)
#define CL 8

__global__ __launch_bounds__(1024) void scan_kernel(
    const uint32_t* __restrict__ qr_ws, const float* __restrict__ g_ws,
    const float* __restrict__ z, const float* __restrict__ mu0,
    const float* __restrict__ P0, float* __restrict__ out)
{
    __shared__ float smem[QT * 17 + QT];
    float* zmu = smem;
    float* gl  = smem + QT * 17;

    const int b = blockIdx.x;
    const int tid = threadIdx.x;
    const int lane = tid & 63;
    const int s = tid >> 6;

    const uint32_t* qrow = qr_ws + (size_t)(b * KS + s) * KT;
    const float* zb = z + (size_t)b * KT * KS;
    const float* gb = g_ws + (size_t)b * KT;
    float* ob = out + (size_t)b * KT * KS;

    float P_q  = P0[b * KS + s];
    float mu_q = mu0[b * KS + s];

    for (int q = 0; q < NQ; ++q) {
        const int t0 = q * QT;

        {
            const float4* zq = reinterpret_cast<const float4*>(zb + (size_t)t0 * KS);
#pragma unroll
            for (int v = 0; v < 2; ++v) {
                int k = tid * 2 + v;
                float4 w = zq[k];
                int t = k >> 2, s0 = (k & 3) << 2;
                zmu[t * 17 + s0 + 0] = w.x;
                zmu[t * 17 + s0 + 1] = w.y;
                zmu[t * 17 + s0 + 2] = w.z;
                zmu[t * 17 + s0 + 3] = w.w;
            }
            if (tid < QT) gl[tid] = gb[t0 + tid];
        }
        __syncthreads();

        uint32_t qr[CL];
        {
            const uint4* qp = reinterpret_cast<const uint4*>(qrow + t0 + lane * CL);
            uint4 u0 = qp[0], u1 = qp[1];
            qr[0] = u0.x; qr[1] = u0.y; qr[2] = u0.z; qr[3] = u0.w;
            qr[4] = u1.x; qr[5] = u1.y; qr[6] = u1.z; qr[7] = u1.w;
        }
        float c00 = 1.f, c01 = 0.f, c10 = 0.f, c11 = 1.f;
#pragma unroll
        for (int i = 0; i < CL; ++i) {
            float Q = h2f_lo(qr[i]), R = h2f_hi(qr[i]);
            float ta = fmaf(Q, c10, c00);
            float tb = fmaf(Q, c11, c01);
            float n10 = fmaf(Q + R, c10, c00);
            float n11 = fmaf(Q + R, c11, c01);
            c00 = R * ta; c01 = R * tb; c10 = n10; c11 = n11;
        }
        float rn = __builtin_amdgcn_rcpf(c11);
        float ma = c00 * rn, mb = c01 * rn, mc = c10 * rn;

#pragma unroll
        for (int r = 0; r < 6; ++r) {
            const int d = 1 << r;
            float pa = __shfl_up(ma, d);
            float pb = __shfl_up(mb, d);
            float pc = __shfl_up(mc, d);
            float na = fmaf(ma, pa, mb * pc);
            float nb = fmaf(ma, pb, mb);
            float nc = fmaf(mc, pa, pc);
            float nd = fmaf(mc, pb, 1.f);
            float rr = __builtin_amdgcn_rcpf(nd);
            bool act = (lane >= d);
            ma = act ? na * rr : ma;
            mb = act ? nb * rr : mb;
            mc = act ? nc * rr : mc;
        }
        float ea = __shfl_up(ma, 1);
        float eb = __shfl_up(mb, 1);
        float ec = __shfl_up(mc, 1);
        if (lane == 0) { ea = 1.f; eb = 0.f; ec = 0.f; }
        float P = fmaf(ea, P_q, eb) * __builtin_amdgcn_rcpf(fmaf(ec, P_q, 1.f));

        float av[CL], bw[CL];
        float A = 1.f, Bv = 0.f;
#pragma unroll
        for (int i = 0; i < CL; ++i) {
            float Q = h2f_lo(qr[i]), R = h2f_hi(qr[i]);
            float Pp = P + Q;
            float K0 = Pp * __builtin_amdgcn_rcpf(Pp + R);
            float Kk = __builtin_amdgcn_fmed3f(K0, 1e-6f, 0.95f);
            int t = lane * CL + i;
            float g = gl[t];
            float gk = g * Kk;
            float zv = zmu[t * 17 + s];
            av[i] = 1.f - gk;
            bw[i] = gk * zv;
            P = fmaf(-Kk, Pp, Pp);
            A = A * av[i];
            Bv = fmaf(av[i], Bv, bw[i]);
        }
        float P_end = __shfl(P, 63);

#pragma unroll
        for (int r = 0; r < 6; ++r) {
            const int d = 1 << r;
            float pA = __shfl_up(A, d);
            float pB = __shfl_up(Bv, d);
            float nA = A * pA;
            float nB = fmaf(A, pB, Bv);
            bool act = (lane >= d);
            A  = act ? nA : A;
            Bv = act ? nB : Bv;
        }
        float eA = __shfl_up(A, 1);
        float eB = __shfl_up(Bv, 1);
        if (lane == 0) { eA = 1.f; eB = 0.f; }
        float mu = fmaf(eA, mu_q, eB);

        __syncthreads();

#pragma unroll
        for (int i = 0; i < CL; ++i) {
            mu = fmaf(av[i], mu, bw[i]);
            zmu[(lane * CL + i) * 17 + s] = mu;
        }
        float mu_end = __shfl(mu, 63);
        __syncthreads();

#pragma unroll
        for (int v = 0; v < 2; ++v) {
            int k = tid * 2 + v;
            int t = k >> 2, s0 = (k & 3) << 2;
            float4 w;
            w.x = zmu[t * 17 + s0 + 0];
            w.y = zmu[t * 17 + s0 + 1];
            w.z = zmu[t * 17 + s0 + 2];
            w.w = zmu[t * 17 + s0 + 3];
            *reinterpret_cast<float4*>(ob + (size_t)(t0 + t) * KS + s0) = w;
        }
        P_q  = P_end;
        mu_q = mu_end;
        __syncthreads();
    }
}

// ---------------- fallback: fused kernel (if ws too small) ----------------
#define KTT 128
#define KNT (KT / KTT)
#define SROW (KS + 1)

__device__ __forceinline__ void mlp16(const float4 pv,
    const float* __restrict__ W1, const float* __restrict__ b1,
    const float* __restrict__ W2, const float* __restrict__ b2,
    float* __restrict__ acc)
{
#pragma unroll
    for (int j = 0; j < KS; ++j) acc[j] = b2[j];
#pragma unroll 4
    for (int k = 0; k < 64; ++k) {
        float hk = b1[k];
        hk = fmaf(pv.x, W1[k],       hk);
        hk = fmaf(pv.y, W1[64 + k],  hk);
        hk = fmaf(pv.z, W1[128 + k], hk);
        hk = fmaf(pv.w, W1[192 + k], hk);
        hk = fmaxf(hk, 0.0f);
#pragma unroll
        for (int j = 0; j < KS; ++j) acc[j] = fmaf(hk, W2[k * KS + j], acc[j]);
    }
}

__global__ __launch_bounds__(320, 2) void kalman_fused(
    const float* __restrict__ z, const float* __restrict__ p,
    const float* __restrict__ mu0, const float* __restrict__ P0,
    const float* __restrict__ Wq1, const float* __restrict__ bq1,
    const float* __restrict__ Wq2, const float* __restrict__ bq2,
    const float* __restrict__ Wr1, const float* __restrict__ br1,
    const float* __restrict__ Wr2, const float* __restrict__ br2,
    const float* __restrict__ Wg1, const float* __restrict__ bg1,
    const float* __restrict__ Wg2, const float* __restrict__ bg2,
    float* __restrict__ out)
{
    __shared__ float sQ[2][KTT][SROW];
    __shared__ float sR[2][KTT][SROW];
    __shared__ float sZf[2][KTT][KS];
    __shared__ float sGf[2][KTT];

    const int b = blockIdx.x;
    const int tid = threadIdx.x;
    const float* __restrict__ zb = z + (size_t)b * KT * KS;
    const float* __restrict__ pb = p + (size_t)b * KT * KPD;
    float* __restrict__ outb = out + (size_t)b * KT * KS;

    const bool is_mlp = (tid < 256);

    auto do_mlp_tile = [&](int tile, int buf) {
        const int tt = tid & (KTT - 1);
        const int t = tile * KTT + tt;
        const float4 pv = *reinterpret_cast<const float4*>(pb + (size_t)t * KPD);
        float acc[KS];
        if (tid < KTT) {
            mlp16(pv, Wq1, bq1, Wq2, bq2, acc);
#pragma unroll
            for (int j = 0; j < KS; ++j)
                sQ[buf][tt][j] = softplus_f(acc[j]) + 1e-8f;
            float ag = bg2[0];
#pragma unroll 8
            for (int k = 0; k < 32; ++k) {
                float hk = bg1[k];
                hk = fmaf(pv.x, Wg1[k],      hk);
                hk = fmaf(pv.y, Wg1[32 + k], hk);
                hk = fmaf(pv.z, Wg1[64 + k], hk);
                hk = fmaf(pv.w, Wg1[96 + k], hk);
                hk = fmaxf(hk, 0.0f);
                ag = fmaf(hk, Wg2[k], ag);
            }
            sGf[buf][tt] = sigmoid_f(ag);
        } else {
            mlp16(pv, Wr1, br1, Wr2, br2, acc);
#pragma unroll
            for (int j = 0; j < KS; ++j)
                sR[buf][tt][j] = softplus_f(acc[j]) + 1e-8f;
        }
        const float4* __restrict__ zt =
            reinterpret_cast<const float4*>(zb + (size_t)tile * KTT * KS);
        float4* __restrict__ zd = reinterpret_cast<float4*>(&sZf[buf][0][0]);
        zd[tid] = zt[tid];
        zd[tid + 256] = zt[tid + 256];
    };

    float mu = 0.0f, Pv = 0.0f;
    if (!is_mlp) {
        const int lane = tid - 256;
        if (lane < KS) {
            mu = mu0[(size_t)b * KS + lane];
            Pv = P0[(size_t)b * KS + lane];
        }
    }

    if (is_mlp) do_mlp_tile(0, 0);
    __syncthreads();

    for (int k = 0; k < KNT; ++k) {
        const int cur = k & 1;
        if (is_mlp) {
            if (k + 1 < KNT) do_mlp_tile(k + 1, cur ^ 1);
        } else {
            const int lane = tid - 256;
            if (lane < KS) {
                const int s = lane;
                for (int tt = 0; tt < KTT; ++tt) {
                    const float Ppred = Pv + sQ[cur][tt][s];
                    float Kk = Ppred * __builtin_amdgcn_rcpf(Ppred + sR[cur][tt][s]);
                    Kk = __builtin_amdgcn_fmed3f(Kk, 1e-6f, 0.95f);
                    mu = fmaf(sGf[cur][tt] * Kk, sZf[cur][tt][s] - mu, mu);
                    Pv = fmaf(-Kk, Ppred, Ppred);
                    outb[(size_t)(k * KTT + tt) * KS + s] = mu;
                }
            }
        }
        __syncthreads();
    }
}

// ---------------- launcher ----------------
extern "C" void kernel_launch(void* const* d_in, const int* in_sizes, int n_in,
                              void* d_out, int out_size, void* d_ws, size_t ws_size,
                              hipStream_t stream) {
    const float* z   = (const float*)d_in[0];
    const float* p   = (const float*)d_in[1];
    const float* mu0 = (const float*)d_in[2];
    const float* P0  = (const float*)d_in[3];
    const float* Wq1 = (const float*)d_in[4];
    const float* bq1 = (const float*)d_in[5];
    const float* Wq2 = (const float*)d_in[6];
    const float* bq2 = (const float*)d_in[7];
    const float* Wr1 = (const float*)d_in[8];
    const float* br1 = (const float*)d_in[9];
    const float* Wr2 = (const float*)d_in[10];
    const float* br2 = (const float*)d_in[11];
    const float* Wg1 = (const float*)d_in[12];
    const float* bg1 = (const float*)d_in[13];
    const float* Wg2 = (const float*)d_in[14];
    const float* bg2 = (const float*)d_in[15];
    float* out = (float*)d_out;

    const size_t QR_BYTES = (size_t)KB * KS * KT * 4;   // 67,108,864
    const size_t G_BYTES  = (size_t)KB * KT * 4;        //  4,194,304

    if (ws_size >= QR_BYTES + G_BYTES) {
        uint32_t* qr_ws = (uint32_t*)d_ws;
        float* g_ws = (float*)((char*)d_ws + QR_BYTES);
        hipLaunchKernelGGL(mlp_kernel, dim3((KB * KT) / 64), dim3(64), 0, stream,
                           p, Wq1, bq1, Wq2, bq2, Wr1, br1, Wr2, br2,
                           Wg1, bg1, Wg2, bg2, qr_ws, g_ws);
        hipLaunchKernelGGL(scan_kernel, dim3(KB), dim3(1024), 0, stream,
                           qr_ws, g_ws, z, mu0, P0, out);
    } else {
        hipLaunchKernelGGL(kalman_fused, dim3(KB), dim3(320), 0, stream,
                           z, p, mu0, P0, Wq1, bq1, Wq2, bq2,
                           Wr1, br1, Wr2, br2, Wg1, bg1, Wg2, bg2, out);
    }
}